// Round 2
// baseline (2455.131 us; speedup 1.0000x reference)
//
#include <hip/hip_runtime.h>
#include <cfloat>
#include <cmath>

// FPS: B=4, N=8192, S=1024. One block per batch; points+ds live in registers
// (8 points/thread x 1024 threads); LDS holds a copy of the cloud for the
// serial "fetch selected point" step and a small double-buffered scratch for
// the cross-wave argmax.

#define NPTS 8192
#define NSAMP 1024
#define TPB 1024
#define PPT (NPTS / TPB)   // 8 points per thread
#define NW (TPB / 64)      // 16 waves

__global__ __launch_bounds__(TPB) void fps_kernel(const float* __restrict__ pts,
                                                  float* __restrict__ out) {
#pragma clang fp contract(off)
    const int b = blockIdx.x;
    const int tid = threadIdx.x;
    const float* __restrict__ P = pts + (size_t)b * NPTS * 3;
    float* __restrict__ O = out + (size_t)b * NSAMP * 3;

    __shared__ float sp[NPTS * 3];      // 96 KB point cloud copy
    __shared__ float swv[2][NW];        // per-wave argmax value (double-buffered)
    __shared__ int   swi[2][NW];        // per-wave argmax index

    float px[PPT], py[PPT], pz[PPT], ds[PPT];

    const float p0x = P[0];
    const float p0y = P[1];
    const float p0z = P[2];

    float mval = -FLT_MAX;
    int   mj   = 0;

    // Load points -> regs + LDS; init ds = ||p - p0|| ; track local argmax.
#pragma unroll
    for (int j = 0; j < PPT; ++j) {
        const int i = j * TPB + tid;          // global point index (stride-TPB layout)
        const float x = P[i * 3 + 0];
        const float y = P[i * 3 + 1];
        const float z = P[i * 3 + 2];
        px[j] = x; py[j] = y; pz[j] = z;
        sp[i * 3 + 0] = x; sp[i * 3 + 1] = y; sp[i * 3 + 2] = z;
        const float dx = x - p0x;
        const float dy = y - p0y;
        const float dz = z - p0z;
        const float sq = dx * dx + dy * dy + dz * dz;   // contraction OFF
        const float d  = sqrtf(sq);
        ds[j] = d;
        if (d > mval) { mval = d; mj = j; }             // strict > : lowest idx on tie
    }
    __syncthreads();

    const int lane = tid & 63;
    const int wid  = tid >> 6;

    for (int s = 0; s < NSAMP; ++s) {
        // ---- wave-level argmax butterfly over (mval, global idx) ----
        float v  = mval;
        int   gi = mj * TPB + tid;
#pragma unroll
        for (int off = 32; off >= 1; off >>= 1) {
            const float ov = __shfl_xor(v, off);
            const int   oi = __shfl_xor(gi, off);
            if (ov > v || (ov == v && oi < gi)) { v = ov; gi = oi; }
        }
        const int buf = s & 1;
        if (lane == 0) { swv[buf][wid] = v; swi[buf][wid] = gi; }
        __syncthreads();

        // ---- every wave redundantly reduces the NW=16 per-wave winners ----
        float vv = swv[buf][lane & (NW - 1)];
        int   ii = swi[buf][lane & (NW - 1)];
#pragma unroll
        for (int off = NW / 2; off >= 1; off >>= 1) {
            const float ov = __shfl_xor(vv, off, NW);
            const int   oi = __shfl_xor(ii, off, NW);
            if (ov > vv || (ov == vv && oi < ii)) { vv = ov; ii = oi; }
        }
        const int gidx = ii;                 // uniform across block

        // selected point coords: LDS broadcast read
        const float sx = sp[gidx * 3 + 0];
        const float sy = sp[gidx * 3 + 1];
        const float sz = sp[gidx * 3 + 2];

        if (tid == 0) {
            O[s * 3 + 0] = sx;
            O[s * 3 + 1] = sy;
            O[s * 3 + 2] = sz;
        }

        // ---- min-update all owned points; track argmax for next iteration ----
        mval = -FLT_MAX; mj = 0;
#pragma unroll
        for (int j = 0; j < PPT; ++j) {
            const float dx = px[j] - sx;
            const float dy = py[j] - sy;
            const float dz = pz[j] - sz;
            const float sq = dx * dx + dy * dy + dz * dz;   // contraction OFF
            const float nd = sqrtf(sq);
            const float d  = fminf(ds[j], nd);
            ds[j] = d;
            if (d > mval) { mval = d; mj = j; }
        }
    }
}

extern "C" void kernel_launch(void* const* d_in, const int* in_sizes, int n_in,
                              void* d_out, int out_size, void* d_ws, size_t ws_size,
                              hipStream_t stream) {
    const float* pts = (const float*)d_in[0];
    float* out = (float*)d_out;
    const int B = in_sizes[0] / (NPTS * 3);   // 4
    fps_kernel<<<B, TPB, 0, stream>>>(pts, out);
}

// Round 3
// 1979.396 us; speedup vs baseline: 1.2403x; 1.2403x over previous
//
#include <hip/hip_runtime.h>
#include <cfloat>
#include <cmath>

// FPS: B=4, N=8192, S=1024. One block per batch; points+ds in registers
// (8 pts/thread x 1024 threads); LDS holds the cloud copy (coord fetch) and
// two tiny double-buffered scalars for the block argmax.
//
// Argmax per iteration (redesigned round 3):
//   thread-local argmax (mval, mj) tracked in the update loop
//   -> 5-step value-only shfl_xor butterfly (32-lane halves)
//   -> half-leaders atomicMax(uint-punned float) into sM[buf]   [order-exact: ds>=0]
//   -> barrier -> threads with mval==M atomicMin their global idx into sIdx[buf]
//      (fmax is exact, so equality is bitwise; atomicMin == argmax first-occurrence
//       tie-break, identical to jnp.argmax)
//   -> barrier -> broadcast read idx + coords.

#define NPTS 8192
#define NSAMP 1024
#define TPB 1024
#define PPT (NPTS / TPB)   // 8 points per thread
#define NW (TPB / 64)      // 16 waves

__global__ __launch_bounds__(TPB) void fps_kernel(const float* __restrict__ pts,
                                                  float* __restrict__ out) {
#pragma clang fp contract(off)
    const int b = blockIdx.x;
    const int tid = threadIdx.x;
    const float* __restrict__ P = pts + (size_t)b * NPTS * 3;
    float* __restrict__ O = out + (size_t)b * NSAMP * 3;

    __shared__ float sp[NPTS * 3];      // 96 KB point cloud copy
    __shared__ unsigned sM[2];          // block max (uint-punned float), dbuf
    __shared__ unsigned sIdx[2];        // block argmax global index, dbuf

    float px[PPT], py[PPT], pz[PPT], ds[PPT];

    const float p0x = P[0];
    const float p0y = P[1];
    const float p0z = P[2];

    float mval = -FLT_MAX;
    int   mj   = 0;

    if (tid == 0) { sM[0] = 0u; sM[1] = 0u; sIdx[0] = 0xFFFFFFFFu; sIdx[1] = 0xFFFFFFFFu; }

    // Load points -> regs + LDS; init ds = ||p - p0||; track thread argmax.
#pragma unroll
    for (int j = 0; j < PPT; ++j) {
        const int i = j * TPB + tid;          // global point index (stride-TPB layout)
        const float x = P[i * 3 + 0];
        const float y = P[i * 3 + 1];
        const float z = P[i * 3 + 2];
        px[j] = x; py[j] = y; pz[j] = z;
        sp[i * 3 + 0] = x; sp[i * 3 + 1] = y; sp[i * 3 + 2] = z;
        const float dx = x - p0x;
        const float dy = y - p0y;
        const float dz = z - p0z;
        const float d  = sqrtf((dx * dx + dy * dy) + dz * dz);   // contraction OFF
        ds[j] = d;
        if (d > mval) { mval = d; mj = j; }   // strict > : lowest j on tie
    }
    __syncthreads();

    const int lane = tid & 63;

    for (int s = 0; s < NSAMP; ++s) {
        const int buf = s & 1;

        // ---- value-only butterfly within each 32-lane half ----
        float wv = mval;
#pragma unroll
        for (int off = 16; off >= 1; off >>= 1)
            wv = fmaxf(wv, __shfl_xor(wv, off));
        if ((lane & 31) == 0)
            atomicMax(&sM[buf], __float_as_uint(wv));   // ds>=0: uint order == float order
        if (tid == 0) { sM[buf ^ 1] = 0u; sIdx[buf ^ 1] = 0xFFFFFFFFu; }  // re-arm other buffer
        __syncthreads();

        // ---- exact index recovery: first-occurrence tie-break via atomicMin ----
        const unsigned Mu = sM[buf];
        if (__float_as_uint(mval) == Mu)
            atomicMin(&sIdx[buf], (unsigned)(mj * TPB + tid));
        __syncthreads();

        const int gidx = (int)sIdx[buf];      // uniform across block
        const float sx = sp[gidx * 3 + 0];    // LDS broadcast reads
        const float sy = sp[gidx * 3 + 1];
        const float sz = sp[gidx * 3 + 2];

        if (tid == 0) {
            O[s * 3 + 0] = sx;
            O[s * 3 + 1] = sy;
            O[s * 3 + 2] = sz;
        }

        // ---- min-update owned points; track thread argmax for next iter ----
        mval = -FLT_MAX; mj = 0;
#pragma unroll
        for (int j = 0; j < PPT; ++j) {
            const float dx = px[j] - sx;
            const float dy = py[j] - sy;
            const float dz = pz[j] - sz;
            const float nd = sqrtf((dx * dx + dy * dy) + dz * dz);  // contraction OFF
            const float d  = fminf(ds[j], nd);
            ds[j] = d;
            if (d > mval) { mval = d; mj = j; }
        }
    }
}

extern "C" void kernel_launch(void* const* d_in, const int* in_sizes, int n_in,
                              void* d_out, int out_size, void* d_ws, size_t ws_size,
                              hipStream_t stream) {
    const float* pts = (const float*)d_in[0];
    float* out = (float*)d_out;
    const int B = in_sizes[0] / (NPTS * 3);   // 4
    fps_kernel<<<B, TPB, 0, stream>>>(pts, out);
}

// Round 5
// 1444.304 us; speedup vs baseline: 1.6999x; 1.3705x over previous
//
#include <hip/hip_runtime.h>
#include <cfloat>
#include <cmath>

// FPS: B=4, N=8192, S=1024. One block per batch; points + running min-distance
// (SQUARED space) in registers, 8 pts/thread x 1024 threads. LDS: cloud copy
// (coord broadcast) + tiny double-buffered argmax scalars.
//
// Exactness: round(sqrt(.)) is monotone non-decreasing => commutes with min/max.
//   dsq_t = min(dsq_{t-1}, ndsq_t)  ==>  round(sqrt(dsq_t)) == ds_ref_t  (induction)
//   U = sqrtf(max_j dsq_j) == max_j ds_ref_j  (exact reference max)
//   tie set {j : sqrtf(dsq_j) == U} == reference argmax tie set; atomicMin over
//   global indices == jnp.argmax first-occurrence tie-break. Bit-exact
//   (verified: round-4 launch_once absmax == 0.0).
//
// Reduction: 6-step DPP max (row_shr 1/2/4/8 + row_bcast 15/31) via
// __builtin_amdgcn_update_dpp — NOT raw inline asm: the VALU->DPP read-after-
// write hazard needs compiler-inserted wait states, and the hazard recognizer
// can't see inside an asm blob (round-4 tripwire root cause). Result lane 63.
//
// Race note: re-arm of buffer buf^1 sits BETWEEN barrier1 and barrier2 — the only
// interval where no thread touches buf^1 (prev iter's gidx read of buf^1 ended at
// barrier1; next iter's atomicMax on buf^1 starts after barrier2).

#define NPTS 8192
#define NSAMP 1024
#define TPB 1024
#define PPT (NPTS / TPB)   // 8 points per thread

__device__ __forceinline__ unsigned wave_max_u32_dpp(unsigned x) {
    unsigned t;
    t = (unsigned)__builtin_amdgcn_update_dpp(0, (int)x, 0x111, 0xF, 0xF, true); // row_shr:1
    x = x > t ? x : t;
    t = (unsigned)__builtin_amdgcn_update_dpp(0, (int)x, 0x112, 0xF, 0xF, true); // row_shr:2
    x = x > t ? x : t;
    t = (unsigned)__builtin_amdgcn_update_dpp(0, (int)x, 0x114, 0xF, 0xF, true); // row_shr:4
    x = x > t ? x : t;
    t = (unsigned)__builtin_amdgcn_update_dpp(0, (int)x, 0x118, 0xF, 0xF, true); // row_shr:8
    x = x > t ? x : t;
    t = (unsigned)__builtin_amdgcn_update_dpp(0, (int)x, 0x142, 0xF, 0xF, true); // row_bcast:15
    x = x > t ? x : t;
    t = (unsigned)__builtin_amdgcn_update_dpp(0, (int)x, 0x143, 0xF, 0xF, true); // row_bcast:31
    x = x > t ? x : t;
    return x;   // lane 63 holds the wave max (values are nonneg-float bits; 0 = identity)
}

__global__ __launch_bounds__(TPB) void fps_kernel(const float* __restrict__ pts,
                                                  float* __restrict__ out) {
#pragma clang fp contract(off)
    const int b = blockIdx.x;
    const int tid = threadIdx.x;
    const float* __restrict__ P = pts + (size_t)b * NPTS * 3;
    float* __restrict__ O = out + (size_t)b * NSAMP * 3;

    __shared__ float sp[NPTS * 3];      // 96 KB point cloud copy
    __shared__ unsigned sM[2];          // block max dsq (uint-punned), dbuf
    __shared__ unsigned sIdx[2];        // block argmax global index, dbuf

    float px[PPT], py[PPT], pz[PPT], dsq[PPT];

    const float p0x = P[0], p0y = P[1], p0z = P[2];

    if (tid == 0) { sM[0] = 0u; sM[1] = 0u; sIdx[0] = 0xFFFFFFFFu; sIdx[1] = 0xFFFFFFFFu; }

    // Load -> regs + LDS; dsq = ||p-p0||^2 (same op order as ref, contraction OFF).
    float tmax = 0.0f;
#pragma unroll
    for (int j = 0; j < PPT; ++j) {
        const int i = j * TPB + tid;          // stride-TPB point ownership
        const float x = P[i * 3 + 0];
        const float y = P[i * 3 + 1];
        const float z = P[i * 3 + 2];
        px[j] = x; py[j] = y; pz[j] = z;
        sp[i * 3 + 0] = x; sp[i * 3 + 1] = y; sp[i * 3 + 2] = z;
        const float dx = x - p0x, dy = y - p0y, dz = z - p0z;
        const float sq = (dx * dx + dy * dy) + dz * dz;
        dsq[j] = sq;
        tmax = fmaxf(tmax, sq);               // all sq >= 0
    }
    __syncthreads();

    const int lane = tid & 63;

    for (int s = 0; s < NSAMP; ++s) {
        const int buf = s & 1;

        // ---- 64-lane max of tmax (uint order == float order for nonneg) ----
        const unsigned wmax = wave_max_u32_dpp(__float_as_uint(tmax));
        const float myU = sqrtf(tmax);               // hoisted off post-barrier chain
        if (lane == 63) atomicMax(&sM[buf], wmax);   // one LDS atomic per wave
        __syncthreads();                              // barrier 1

        // ---- exact argmax-index recovery in sqrt space ----
        const float U = sqrtf(__uint_as_float(sM[buf]));   // == reference max ds
        if (myU == U) {                               // thread holds >=1 tie candidate
            int cj = 0;
#pragma unroll
            for (int j = PPT - 1; j >= 0; --j)
                if (sqrtf(dsq[j]) == U) cj = j;       // descending: ends at smallest j
            atomicMin(&sIdx[buf], (unsigned)(cj * TPB + tid));
        }
        if (tid == 0) { sM[buf ^ 1] = 0u; sIdx[buf ^ 1] = 0xFFFFFFFFu; }  // re-arm (safe slot)
        __syncthreads();                              // barrier 2

        const int gidx = (int)sIdx[buf];              // uniform
        const float sx = sp[gidx * 3 + 0];
        const float sy = sp[gidx * 3 + 1];
        const float sz = sp[gidx * 3 + 2];

        if (tid == 0) {
            O[s * 3 + 0] = sx;
            O[s * 3 + 1] = sy;
            O[s * 3 + 2] = sz;
        }

        // ---- min-update in squared space: 10 VALU/pt, no sqrt ----
        tmax = 0.0f;
#pragma unroll
        for (int j = 0; j < PPT; ++j) {
            const float dx = px[j] - sx;
            const float dy = py[j] - sy;
            const float dz = pz[j] - sz;
            const float nd = (dx * dx + dy * dy) + dz * dz;   // contraction OFF
            const float d  = fminf(dsq[j], nd);
            dsq[j] = d;
            tmax = fmaxf(tmax, d);
        }
    }
}

extern "C" void kernel_launch(void* const* d_in, const int* in_sizes, int n_in,
                              void* d_out, int out_size, void* d_ws, size_t ws_size,
                              hipStream_t stream) {
    const float* pts = (const float*)d_in[0];
    float* out = (float*)d_out;
    const int B = in_sizes[0] / (NPTS * 3);   // 4
    fps_kernel<<<B, TPB, 0, stream>>>(pts, out);
}